// Round 2
// baseline (32.206 us; speedup 1.0000x reference)
//
#include <hip/hip_runtime.h>

// Shapes: proposals (16, 32768, 4) f32, gt_boxes (16, 64, 5) f32
//      -> out (16, 32768, 5) f32.
#define BATCH 16
#define NPROP 32768
#define NGT   64
#define BLOCK 256

// ---------------------------------------------------------------------------
// Prep: clean GT boxes once into ws as (B, NGT, 8) floats:
//   [x1, y1, x2, y2, area2, cls, 0, 0]
// Invalid boxes (cls == -1) become a far-away zero-intersection box with
// area2 = 1 -> iou = 0. Output-equivalence argument: index differences vs the
// reference's iou=-1 encoding only occur when the final output is -1 anyway.
// ---------------------------------------------------------------------------
__global__ void prep_kernel(const float* __restrict__ gt, float* __restrict__ ws) {
    const int t = blockIdx.x * blockDim.x + threadIdx.x;   // 0 .. B*NGT-1
    if (t >= BATCH * NGT) return;
    const float* g = gt + (size_t)t * 5;
    float x1 = g[0], y1 = g[1], x2 = g[2], y2 = g[3], c = g[4];
    float a2 = (x2 - x1) * (y2 - y1);
    if (c == -1.0f) { x1 = y1 = x2 = y2 = -1.0e4f; a2 = 1.0f; }
    float* w = ws + (size_t)t * 8;
    w[0] = x1; w[1] = y1; w[2] = x2; w[3] = y2;
    w[4] = a2; w[5] = c;  w[6] = 0.f; w[7] = 0.f;
}

// ---------------------------------------------------------------------------
// Main: one thread per proposal. Box data is wave-uniform -> the compiler
// lowers the cleaned-box reads to s_load (scalar pipe, constant cache),
// leaving the inner loop pure VALU with ZERO LDS instructions.
// Argmax via cross-multiplication (dens > 0); strict '>' keeps jnp.argmax
// first-occurrence semantics. One exact division at the end reproduces the
// numpy operand order for the 0.5 / 0.6 boundary compares.
// ---------------------------------------------------------------------------
__global__ __launch_bounds__(BLOCK) void match_kernel(
    const float* __restrict__ props,   // (B, N, 4)
    const float* __restrict__ gt,      // (B, M, 5) original
    const float* __restrict__ cln,     // (B, M, 8) cleaned
    float* __restrict__ out)           // (B, N, 5)
{
    const int blocksPerBatch = NPROP / BLOCK;            // 128
    const int b = blockIdx.x / blocksPerBatch;
    const int n = (blockIdx.x % blocksPerBatch) * BLOCK + threadIdx.x;

    const float4 p = reinterpret_cast<const float4*>(props)[(size_t)b * NPROP + n];
    const float area1 = (p.z - p.x) * (p.w - p.y);

    const float* cb = cln + (size_t)b * NGT * 8;         // uniform base

    float bestNum = -1.0f;   // iou = -1 sentinel: box 0 always wins first
    float bestDen = 1.0f;
    int   besti   = 0;

    #pragma unroll 16
    for (int m = 0; m < NGT; ++m) {
        const float gx1 = cb[m * 8 + 0];
        const float gy1 = cb[m * 8 + 1];
        const float gx2 = cb[m * 8 + 2];
        const float gy2 = cb[m * 8 + 3];
        const float a2  = cb[m * 8 + 4];

        const float ix1 = fmaxf(p.x, gx1);
        const float iy1 = fmaxf(p.y, gy1);
        const float ix2 = fminf(p.z, gx2);
        const float iy2 = fminf(p.w, gy2);
        const float inter = fmaxf(ix2 - ix1, 0.0f) * fmaxf(iy2 - iy1, 0.0f);
        const float den   = (area1 + a2) - inter;        // numpy order

        const bool better = inter * bestDen > bestNum * den;
        bestNum = better ? inter : bestNum;
        bestDen = better ? den   : bestDen;
        besti   = better ? m     : besti;
    }

    const float q = bestNum / bestDen;   // one exact division

    float o0, o1, o2, o3, o4;
    if (q <= 0.5f) {
        o0 = o1 = o2 = o3 = o4 = -1.0f;
    } else if (q < 0.6f) {
        o0 = o1 = o2 = o3 = o4 = -1.0e8f;
    } else {
        // Gather the ORIGINAL gt row (coords + class). Divergent index, but
        // the whole per-batch table is 1280 B -> L1 hits.
        const float* g0 = gt + ((size_t)b * NGT + besti) * 5;
        o0 = g0[0]; o1 = g0[1]; o2 = g0[2]; o3 = g0[3]; o4 = g0[4];
    }

    float* op = out + ((size_t)b * NPROP + n) * 5;
    op[0] = o0; op[1] = o1; op[2] = o2; op[3] = o3; op[4] = o4;
}

extern "C" void kernel_launch(void* const* d_in, const int* in_sizes, int n_in,
                              void* d_out, int out_size, void* d_ws, size_t ws_size,
                              hipStream_t stream) {
    const float* props = (const float*)d_in[0];
    const float* gt    = (const float*)d_in[1];
    float* out = (float*)d_out;
    float* cln = (float*)d_ws;                 // needs B*NGT*8*4 = 32 KiB

    prep_kernel<<<(BATCH * NGT + BLOCK - 1) / BLOCK, BLOCK, 0, stream>>>(gt, cln);

    const int grid = BATCH * (NPROP / BLOCK);  // 2048 blocks
    match_kernel<<<grid, BLOCK, 0, stream>>>(props, gt, cln, out);
}

// Round 3
// 23.449 us; speedup vs baseline: 1.3734x; 1.3734x over previous
//
#include <hip/hip_runtime.h>

// Shapes: proposals (16, 32768, 4) f32, gt_boxes (16, 64, 5) f32
//      -> out (16, 32768, 5) f32.
#define BATCH 16
#define NPROP 32768
#define NGT   64
#define BLOCK 256
#define P     4                      // proposals per thread

__global__ __launch_bounds__(BLOCK) void match_kernel(
    const float* __restrict__ props,   // (B, N, 4)
    const float* __restrict__ gt,      // (B, M, 5)
    float* __restrict__ out)           // (B, N, 5)
{
    // Cleaned boxes: [x1, y1, x2, y2, area2, cls, pad, pad], 32B stride.
    // float4-aligned so the loop reads ds_read_b128 + ds_read_b32 per box.
    __shared__ float sgt[NGT][8];

    const int blocksPerBatch = NPROP / (BLOCK * P);        // 32
    const int b    = blockIdx.x / blocksPerBatch;
    const int base = (blockIdx.x % blocksPerBatch) * (BLOCK * P);

    // Stage + clean GT boxes once per block. Invalid (cls == -1) becomes a
    // far-away zero-intersection box with area2 = 1 -> iou = 0; index
    // differences vs the reference's -1 encoding only occur when the final
    // output is -1 anyway (all-invalid => q=0 <= 0.5 => -1 fill).
    if (threadIdx.x < NGT) {
        const float* g = gt + ((size_t)b * NGT + threadIdx.x) * 5;
        float x1 = g[0], y1 = g[1], x2 = g[2], y2 = g[3], c = g[4];
        float a2 = (x2 - x1) * (y2 - y1);
        if (c == -1.0f) { x1 = y1 = x2 = y2 = -1.0e4f; a2 = 1.0f; }
        sgt[threadIdx.x][0] = x1;
        sgt[threadIdx.x][1] = y1;
        sgt[threadIdx.x][2] = x2;
        sgt[threadIdx.x][3] = y2;
        sgt[threadIdx.x][4] = a2;
        sgt[threadIdx.x][5] = c;
    }
    __syncthreads();

    // Load P proposals, strided by BLOCK for coalescing.
    const float4* pv = reinterpret_cast<const float4*>(props)
                     + (size_t)b * NPROP + base + threadIdx.x;
    float4 p[P];
    float  a1[P];
    #pragma unroll
    for (int k = 0; k < P; ++k) {
        p[k]  = pv[k * BLOCK];
        a1[k] = (p[k].z - p[k].x) * (p[k].w - p[k].y);
    }

    // Argmax over IoU fractions via cross-multiplication (dens > 0);
    // strict '>' keeps jnp.argmax first-occurrence semantics.
    float bn[P], bd[P];
    int   bi[P];
    #pragma unroll
    for (int k = 0; k < P; ++k) { bn[k] = -1.0f; bd[k] = 1.0f; bi[k] = 0; }

    #pragma unroll 8
    for (int m = 0; m < NGT; ++m) {
        const float4 g  = *reinterpret_cast<const float4*>(&sgt[m][0]);
        const float  a2 = sgt[m][4];
        #pragma unroll
        for (int k = 0; k < P; ++k) {
            const float ix1 = fmaxf(p[k].x, g.x);
            const float iy1 = fmaxf(p[k].y, g.y);
            const float ix2 = fminf(p[k].z, g.z);
            const float iy2 = fminf(p[k].w, g.w);
            const float inter = fmaxf(ix2 - ix1, 0.0f) * fmaxf(iy2 - iy1, 0.0f);
            const float den   = (a1[k] + a2) - inter;      // numpy order

            const bool better = inter * bd[k] > bn[k] * den;
            bn[k] = better ? inter : bn[k];
            bd[k] = better ? den   : bd[k];
            bi[k] = better ? m     : bi[k];
        }
    }

    // Branch-free epilogue: one exact division per proposal (numpy operand
    // order for the 0.5/0.6 boundary compares), unconditional LDS gather,
    // then selects.
    #pragma unroll
    for (int k = 0; k < P; ++k) {
        const float q = bn[k] / bd[k];
        const float4 g  = *reinterpret_cast<const float4*>(&sgt[bi[k]][0]);
        const float  gc = sgt[bi[k]][5];

        const bool bg      = (q <= 0.5f);
        const bool neutral = (q > 0.5f) & (q < 0.6f);
        const float fill   = neutral ? -1.0e8f : -1.0f;
        const bool keep    = !(bg | neutral);

        float* op = out + ((size_t)b * NPROP + base + threadIdx.x + k * BLOCK) * 5;
        op[0] = keep ? g.x : fill;
        op[1] = keep ? g.y : fill;
        op[2] = keep ? g.z : fill;
        op[3] = keep ? g.w : fill;
        op[4] = keep ? gc  : fill;
    }
}

extern "C" void kernel_launch(void* const* d_in, const int* in_sizes, int n_in,
                              void* d_out, int out_size, void* d_ws, size_t ws_size,
                              hipStream_t stream) {
    const float* props = (const float*)d_in[0];
    const float* gt    = (const float*)d_in[1];
    float* out = (float*)d_out;

    const int grid = BATCH * (NPROP / (BLOCK * P));   // 512 blocks
    match_kernel<<<grid, BLOCK, 0, stream>>>(props, gt, out);
}

// Round 4
// 22.683 us; speedup vs baseline: 1.4198x; 1.0338x over previous
//
#include <hip/hip_runtime.h>

// Shapes: proposals (16, 32768, 4) f32, gt_boxes (16, 64, 5) f32
//      -> out (16, 32768, 5) f32.
#define BATCH 16
#define NPROP 32768
#define NGT   64
#define BLOCK 256
#define P     2                      // proposals per thread

__global__ __launch_bounds__(BLOCK) void match_kernel(
    const float* __restrict__ props,   // (B, N, 4)
    const float* __restrict__ gt,      // (B, M, 5)
    float* __restrict__ out)           // (B, N, 5)
{
    // Cleaned boxes, split arrays: float4 coords (ds_read_b128) + a2 + cls.
    __shared__ float4 sbox[NGT];
    __shared__ float  sa2[NGT];
    __shared__ float  scls[NGT];

    const int blocksPerBatch = NPROP / (BLOCK * P);        // 64
    const int b    = blockIdx.x / blocksPerBatch;
    const int base = (blockIdx.x % blocksPerBatch) * (BLOCK * P);

    // Stage + clean GT boxes once per block. Invalid (cls == -1) becomes a
    // far-away zero-intersection box with area2 = 1 -> iou = 0; index
    // differences vs the reference's -1 encoding only occur when the final
    // output is -1 anyway (all-invalid => q = 0 <= 0.5 => -1 fill).
    if (threadIdx.x < NGT) {
        const float* g = gt + ((size_t)b * NGT + threadIdx.x) * 5;
        float x1 = g[0], y1 = g[1], x2 = g[2], y2 = g[3], c = g[4];
        float a2 = (x2 - x1) * (y2 - y1);
        if (c == -1.0f) { x1 = y1 = x2 = y2 = -1.0e4f; a2 = 1.0f; }
        sbox[threadIdx.x] = make_float4(x1, y1, x2, y2);
        sa2[threadIdx.x]  = a2;
        scls[threadIdx.x] = c;
    }
    __syncthreads();

    // Load P proposals, strided by BLOCK for coalescing.
    const float4* pv = reinterpret_cast<const float4*>(props)
                     + (size_t)b * NPROP + base + threadIdx.x;
    float4 p[P];
    float  a1[P];
    #pragma unroll
    for (int k = 0; k < P; ++k) {
        p[k]  = pv[k * BLOCK];
        a1[k] = (p[k].z - p[k].x) * (p[k].w - p[k].y);
    }

    // Argmax over IoU fractions via cross-multiplication (dens > 0);
    // strict '>' keeps jnp.argmax first-occurrence semantics.
    float bn[P], bd[P];
    int   bi[P];
    #pragma unroll
    for (int k = 0; k < P; ++k) { bn[k] = -1.0f; bd[k] = 1.0f; bi[k] = 0; }

    #pragma unroll 8
    for (int m = 0; m < NGT; ++m) {
        const float4 g  = sbox[m];
        const float  a2 = sa2[m];
        #pragma unroll
        for (int k = 0; k < P; ++k) {
            const float ix1 = fmaxf(p[k].x, g.x);
            const float iy1 = fmaxf(p[k].y, g.y);
            const float ix2 = fminf(p[k].z, g.z);
            const float iy2 = fminf(p[k].w, g.w);
            const float inter = fmaxf(ix2 - ix1, 0.0f) * fmaxf(iy2 - iy1, 0.0f);
            const float den   = (a1[k] + a2) - inter;      // numpy order

            const bool better = inter * bd[k] > bn[k] * den;
            bn[k] = better ? inter : bn[k];
            bd[k] = better ? den   : bd[k];
            bi[k] = better ? m     : bi[k];
        }
    }

    // Branch-free epilogue: one exact division per proposal (numpy operand
    // order for the 0.5/0.6 boundary compares), unconditional LDS gather,
    // then selects.
    #pragma unroll
    for (int k = 0; k < P; ++k) {
        const float q  = bn[k] / bd[k];
        const float4 g = sbox[bi[k]];
        const float gc = scls[bi[k]];

        const bool bg      = (q <= 0.5f);
        const bool neutral = (q > 0.5f) & (q < 0.6f);
        const float fill   = neutral ? -1.0e8f : -1.0f;
        const bool keep    = !(bg | neutral);

        float* op = out + ((size_t)b * NPROP + base + threadIdx.x + k * BLOCK) * 5;
        op[0] = keep ? g.x : fill;
        op[1] = keep ? g.y : fill;
        op[2] = keep ? g.z : fill;
        op[3] = keep ? g.w : fill;
        op[4] = keep ? gc  : fill;
    }
}

extern "C" void kernel_launch(void* const* d_in, const int* in_sizes, int n_in,
                              void* d_out, int out_size, void* d_ws, size_t ws_size,
                              hipStream_t stream) {
    const float* props = (const float*)d_in[0];
    const float* gt    = (const float*)d_in[1];
    float* out = (float*)d_out;

    const int grid = BATCH * (NPROP / (BLOCK * P));   // 1024 blocks
    match_kernel<<<grid, BLOCK, 0, stream>>>(props, gt, out);
}